// Round 8
// baseline (254.617 us; speedup 1.0000x reference)
//
#include <hip/hip_runtime.h>
#include <cstdint>
#include <cstddef>

// ---------------------------------------------------------------------------
// GCN: 3 layers, shared graph.
//   - Agg passes are bound by COMPULSORY per-XCD L2-fill traffic (~82MB/pass
//     at ~1.7TB/s L3->L2 fill = ~48us); random graph -> every XCD first-
//     touches ~86% of the 12.8MB bf16 feature table. R7's issue-rate theory
//     was falsified (pairing was neutral). This round: 8-pair-deep pipeline
//     as a final MLP test; if flat, aggs are at their structural floor.
//   - Features between stages packed bf16x2 (halves gather bytes).
//   - GEMMs: bf16 MFMA 16x16x32, C written via LDS transpose (16B stores).
//   - Layer 3 via linearity + fused projection/log_softmax (butterfly).
// ---------------------------------------------------------------------------

typedef unsigned int uint;
typedef unsigned short u16;
typedef uint  uint4e  __attribute__((ext_vector_type(4)));
typedef float float4e __attribute__((ext_vector_type(4)));
typedef uint  uint2e  __attribute__((ext_vector_type(2)));
typedef int   int2e   __attribute__((ext_vector_type(2)));
typedef int   int4e   __attribute__((ext_vector_type(4)));
using bf16x8 = __attribute__((ext_vector_type(8))) short;
using f32x4  = __attribute__((ext_vector_type(4))) float;

__device__ __forceinline__ float bf_lo(uint v) { return __uint_as_float(v << 16); }
__device__ __forceinline__ float bf_hi(uint v) { return __uint_as_float(v & 0xffff0000u); }
__device__ __forceinline__ u16 bf16_1(float a) {
    uint ua = __float_as_uint(a);
    ua = (ua + 0x7fffu + ((ua >> 16) & 1u)) >> 16;          // RNE
    return (u16)ua;
}
__device__ __forceinline__ uint pack_bf2(float a, float b) {
    return (uint)bf16_1(a) | ((uint)bf16_1(b) << 16);
}

__global__ void count_kernel(const int* __restrict__ ei, int E, int* __restrict__ cnt) {
    int i = blockIdx.x * blockDim.x + threadIdx.x;
    int stride = gridDim.x * blockDim.x;
    int nG = E >> 2;
    for (int g = i; g < nG; g += stride) {
        int4e d = *reinterpret_cast<const int4e*>(ei + E + g * 4);
        atomicAdd(&cnt[d.x], 1);
        atomicAdd(&cnt[d.y], 1);
        atomicAdd(&cnt[d.z], 1);
        atomicAdd(&cnt[d.w], 1);
    }
    for (int e = nG * 4 + i; e < E; e += stride) atomicAdd(&cnt[ei[E + e]], 1);
}

// Pass 1: per-block (1024 elems) totals; also computes dis = rsqrt(deg+1).
__global__ __launch_bounds__(256) void scan_partial(const int* __restrict__ cnt,
        int* __restrict__ bsum, float* __restrict__ dis, int n) {
    __shared__ int red[256];
    int b = blockIdx.x, tid = threadIdx.x;
    int base = b * 1024 + tid * 4;
    int4 v = make_int4(0, 0, 0, 0);
    if (base + 4 <= n) {
        v = *reinterpret_cast<const int4*>(cnt + base);
    } else {
        if (base + 0 < n) v.x = cnt[base + 0];
        if (base + 1 < n) v.y = cnt[base + 1];
        if (base + 2 < n) v.z = cnt[base + 2];
    }
    if (base + 0 < n) dis[base + 0] = rsqrtf((float)(v.x + 1));
    if (base + 1 < n) dis[base + 1] = rsqrtf((float)(v.y + 1));
    if (base + 2 < n) dis[base + 2] = rsqrtf((float)(v.z + 1));
    if (base + 3 < n) dis[base + 3] = rsqrtf((float)(v.w + 1));
    red[tid] = v.x + v.y + v.z + v.w;
    __syncthreads();
    for (int d = 128; d > 0; d >>= 1) {
        if (tid < d) red[tid] += red[tid + d];
        __syncthreads();
    }
    if (tid == 0) bsum[b] = red[0];
}

// Pass 2: wave 0 redundantly scans block sums for this block's offset, then
// block-local exclusive scan + offset -> row_ptr.
__global__ __launch_bounds__(256) void scan_final(const int* __restrict__ cnt,
        const int* __restrict__ bsum, int* __restrict__ row_ptr, int nb, int n) {
    __shared__ int red[256];
    __shared__ int sh_boff;
    int b = blockIdx.x, tid = threadIdx.x;
    if (tid < 64) {
        int s = (tid < nb) ? bsum[tid] : 0;
        int v = s;
        for (int d = 1; d < 64; d <<= 1) {
            int t = __shfl_up(v, d);
            if (tid >= d) v += t;
        }
        if (tid == b) sh_boff = v - s;                 // exclusive offset of this block
        if (b == 0 && tid == 63) row_ptr[n] = v;       // grand total
    }
    int base = b * 1024 + tid * 4;
    int4 v = make_int4(0, 0, 0, 0);
    if (base + 4 <= n) {
        v = *reinterpret_cast<const int4*>(cnt + base);
    } else {
        if (base + 0 < n) v.x = cnt[base + 0];
        if (base + 1 < n) v.y = cnt[base + 1];
        if (base + 2 < n) v.z = cnt[base + 2];
    }
    int s = v.x + v.y + v.z + v.w;
    red[tid] = s;
    __syncthreads();
    for (int d = 1; d < 256; d <<= 1) {
        int t = (tid >= d) ? red[tid - d] : 0;
        __syncthreads();
        red[tid] += t;
        __syncthreads();
    }
    int off = sh_boff + red[tid] - s;
    if (base + 0 < n) { row_ptr[base + 0] = off; off += v.x; }
    if (base + 1 < n) { row_ptr[base + 1] = off; off += v.y; }
    if (base + 2 < n) { row_ptr[base + 2] = off; off += v.z; }
    if (base + 3 < n) { row_ptr[base + 3] = off; }
}

__global__ void fill_kernel(const int* __restrict__ ei, int E,
                            const int* __restrict__ row_ptr, int* __restrict__ fillc,
                            const float* __restrict__ dis, int2e* __restrict__ esort) {
    int i = blockIdx.x * blockDim.x + threadIdx.x;
    int stride = gridDim.x * blockDim.x;
    int nG = E >> 2;
    for (int g = i; g < nG; g += stride) {
        int4e s4 = *reinterpret_cast<const int4e*>(ei + g * 4);
        int4e d4 = *reinterpret_cast<const int4e*>(ei + E + g * 4);
#pragma unroll
        for (int k = 0; k < 4; ++k) {
            int s = k == 0 ? s4.x : k == 1 ? s4.y : k == 2 ? s4.z : s4.w;
            int d = k == 0 ? d4.x : k == 1 ? d4.y : k == 2 ? d4.z : d4.w;
            int pos = row_ptr[d] + atomicAdd(&fillc[d], 1);
            int2e pkt;
            pkt.x = s;
            pkt.y = __float_as_int(dis[s] * dis[d]);
            esort[pos] = pkt;
        }
    }
    for (int e = nG * 4 + i; e < E; e += stride) {
        int s = ei[e];
        int d = ei[E + e];
        int pos = row_ptr[d] + atomicAdd(&fillc[d], 1);
        int2e pkt;
        pkt.x = s;
        pkt.y = __float_as_int(dis[s] * dis[d]);
        esort[pos] = pkt;
    }
}

// One-time: Wt[c][k] = bf16(W[k][c]) for both weight matrices (blockIdx picks).
__global__ __launch_bounds__(256) void wt_kernel(const float* __restrict__ Wa,
        const float* __restrict__ Wb, u16* __restrict__ Wta, u16* __restrict__ Wtb) {
    const float* W = blockIdx.x ? Wb : Wa;
    u16* Wt = blockIdx.x ? Wtb : Wta;
    int tid = threadIdx.x;
    for (int i = 0; i < 64; ++i) {
        int idx = tid + i * 256;          // 16384 = 128*128
        int k = idx >> 7, c = idx & 127;
        Wt[c * 128 + k] = bf16_1(W[idx]); // read coalesced, write scattered (once)
    }
}

// out u16[n][128] = bf16( A[n][128] @ W ),  W given as Wt bf16 [col][k].
// C is written via LDS round-trip -> fully coalesced 16B stores.
template <typename TA>
__global__ __launch_bounds__(256) void gemm_mfma(const TA* __restrict__ A,
        const u16* __restrict__ Wt, u16* __restrict__ out, int n) {
    constexpr int LDA = 136;                 // 128 + 8 pad (bf16) -> 2-way LDS only
    __shared__ u16 as[64 * LDA];
    int tid = threadIdx.x;
    int wave = tid >> 6, lane = tid & 63;
    int row0 = blockIdx.x * 64;
    int l16 = lane & 15;
    int krow = (lane >> 4) * 8;              // k-octet within 32-wide K block

    if constexpr (sizeof(TA) == 4) {
#pragma unroll
        for (int i = 0; i < 8; ++i) {
            int idx = tid + i * 256;         // 2048 quads of 4 f32
            int r = idx >> 5;
            int q = (idx & 31) * 4;
            float4e v = {0.f, 0.f, 0.f, 0.f};
            if (row0 + r < n)
                v = *reinterpret_cast<const float4e*>((const float*)A + (size_t)(row0 + r) * 128 + q);
            uint2e p;
            p.x = pack_bf2(v.x, v.y);
            p.y = pack_bf2(v.z, v.w);
            *reinterpret_cast<uint2e*>(&as[r * LDA + q]) = p;
        }
    } else {
#pragma unroll
        for (int i = 0; i < 4; ++i) {
            int idx = tid + i * 256;         // 1024 octs of 8 bf16
            int r = idx >> 4;
            int q = (idx & 15) * 8;
            uint4e v = {0u, 0u, 0u, 0u};
            if (row0 + r < n)
                v = *reinterpret_cast<const uint4e*>((const u16*)A + (size_t)(row0 + r) * 128 + q);
            *reinterpret_cast<uint4e*>(&as[r * LDA + q]) = v;
        }
    }

    bf16x8 b[2][4];
#pragma unroll
    for (int n2 = 0; n2 < 2; ++n2)
#pragma unroll
        for (int kb = 0; kb < 4; ++kb)
            b[n2][kb] = *reinterpret_cast<const bf16x8*>(
                Wt + (size_t)(wave * 32 + n2 * 16 + l16) * 128 + kb * 32 + krow);

    __syncthreads();

    f32x4 acc[4][2] = {};
#pragma unroll
    for (int m = 0; m < 4; ++m) {
#pragma unroll
        for (int kb = 0; kb < 4; ++kb) {
            bf16x8 a = *reinterpret_cast<const bf16x8*>(
                &as[(m * 16 + l16) * LDA + kb * 32 + krow]);
#pragma unroll
            for (int n2 = 0; n2 < 2; ++n2)
                acc[m][n2] = __builtin_amdgcn_mfma_f32_16x16x32_bf16(a, b[n2][kb], acc[m][n2], 0, 0, 0);
        }
    }

    // ---- C via LDS: bf16 into cs[row][col] (stride 128), then 16B stores ----
    __syncthreads();                         // as[] reuse
    u16* cs = as;
#pragma unroll
    for (int m = 0; m < 4; ++m) {
        int rb = m * 16 + (lane >> 4) * 4;
#pragma unroll
        for (int n2 = 0; n2 < 2; ++n2) {
            int col = wave * 32 + n2 * 16 + l16;
#pragma unroll
            for (int r = 0; r < 4; ++r)
                cs[(rb + r) * 128 + col] = bf16_1(acc[m][n2][r]);
        }
    }
    __syncthreads();
#pragma unroll
    for (int i = 0; i < 4; ++i) {
        int idx = tid + i * 256;             // 1024 octs: row=idx>>4, oct=(idx&15)
        int r = idx >> 4;
        int q = (idx & 15) * 8;
        if (row0 + r < n)
            *reinterpret_cast<uint4e*>(out + (size_t)(row0 + r) * 128 + q) =
                *reinterpret_cast<const uint4e*>(&cs[r * 128 + q]);
    }
}

// Half-wave paired gather: lanes 0-31 even edges, 32-63 odd edges; 4 dims/lane.
// 8 pairs (16 edges) in flight in the main loop.
// On return, ALL lanes hold combined a0..a3 = node dims [4j .. 4j+3], j=lane&31.
__device__ __forceinline__ void gather_accum2(const uint* __restrict__ xw,
        const int2e* __restrict__ esort, const float* __restrict__ dis,
        int v, int half, int j, int beg, int end,
        float& a0, float& a1, float& a2, float& a3) {
    int e = beg;
    for (; e + 15 < end; e += 16) {                     // 16 edges, 8 gathers in flight
        int2e ed[8];
        uint2e r[8];
#pragma unroll
        for (int p = 0; p < 8; ++p) ed[p] = esort[e + 2 * p + half];
#pragma unroll
        for (int p = 0; p < 8; ++p)
            r[p] = *reinterpret_cast<const uint2e*>(xw + (size_t)ed[p].x * 64 + j * 2);
#pragma unroll
        for (int p = 0; p < 8; ++p) {
            float w = __int_as_float(ed[p].y);
            a0 += w * bf_lo(r[p].x); a1 += w * bf_hi(r[p].x);
            a2 += w * bf_lo(r[p].y); a3 += w * bf_hi(r[p].y);
        }
    }
    if (e + 7 < end) {                                  // 8-edge tail
        int2e ed[4];
        uint2e r[4];
#pragma unroll
        for (int p = 0; p < 4; ++p) ed[p] = esort[e + 2 * p + half];
#pragma unroll
        for (int p = 0; p < 4; ++p)
            r[p] = *reinterpret_cast<const uint2e*>(xw + (size_t)ed[p].x * 64 + j * 2);
#pragma unroll
        for (int p = 0; p < 4; ++p) {
            float w = __int_as_float(ed[p].y);
            a0 += w * bf_lo(r[p].x); a1 += w * bf_hi(r[p].x);
            a2 += w * bf_lo(r[p].y); a3 += w * bf_hi(r[p].y);
        }
        e += 8;
    }
    for (; e + 1 < end; e += 2) {                       // pair tail
        int2e ed = esort[e + half];
        uint2e r = *reinterpret_cast<const uint2e*>(xw + (size_t)ed.x * 64 + j * 2);
        float w = __int_as_float(ed.y);
        a0 += w * bf_lo(r.x); a1 += w * bf_hi(r.x);
        a2 += w * bf_lo(r.y); a3 += w * bf_hi(r.y);
    }
    if (e < end) {                                      // odd single: half 0 only
        int2e ed = esort[e];
        uint2e r = *reinterpret_cast<const uint2e*>(xw + (size_t)ed.x * 64 + j * 2);
        float w = half ? 0.f : __int_as_float(ed.y);
        a0 += w * bf_lo(r.x); a1 += w * bf_hi(r.x);
        a2 += w * bf_lo(r.y); a3 += w * bf_hi(r.y);
    }
    {                                                   // self-loop: half 0 only
        float dv = dis[v];
        float wv = half ? 0.f : dv * dv;
        uint2e r = *reinterpret_cast<const uint2e*>(xw + (size_t)v * 64 + j * 2);
        a0 += wv * bf_lo(r.x); a1 += wv * bf_hi(r.x);
        a2 += wv * bf_lo(r.y); a3 += wv * bf_hi(r.y);
    }
    a0 += __shfl_xor(a0, 32);                           // merge halves (symmetric)
    a1 += __shfl_xor(a1, 32);
    a2 += __shfl_xor(a2, 32);
    a3 += __shfl_xor(a3, 32);
}

// CSR aggregation -> packed bf16. MODE: 1 = +bias, 2 = +bias+relu.
template <int MODE>
__global__ __launch_bounds__(256) void agg_kernel(const uint* __restrict__ xw,
        const int* __restrict__ row_ptr, const int2e* __restrict__ esort,
        const float* __restrict__ dis, const float* __restrict__ bias,
        uint* __restrict__ out, int n) {
    int v = (int)((blockIdx.x * blockDim.x + threadIdx.x) >> 6);
    int lane = threadIdx.x & 63;
    if (v >= n) return;
    int half = lane >> 5, j = lane & 31;
    float a0 = 0.f, a1 = 0.f, a2 = 0.f, a3 = 0.f;
    gather_accum2(xw, esort, dis, v, half, j, row_ptr[v], row_ptr[v + 1], a0, a1, a2, a3);
    float4e bv = *reinterpret_cast<const float4e*>(bias + j * 4);
    a0 += bv.x; a1 += bv.y; a2 += bv.z; a3 += bv.w;
    if (MODE == 2) {
        a0 = fmaxf(a0, 0.f); a1 = fmaxf(a1, 0.f);
        a2 = fmaxf(a2, 0.f); a3 = fmaxf(a3, 0.f);
    }
    if (!half) {
        uint2e o = {pack_bf2(a0, a1), pack_bf2(a2, a3)};
        *reinterpret_cast<uint2e*>(out + (size_t)v * 64 + j * 2) = o;
    }
}

// Final layer fused: h = Agg(h2); out = log_softmax(h @ W3 + b3).
__global__ __launch_bounds__(256) void agg_out_kernel(const uint* __restrict__ xw,
        const int* __restrict__ row_ptr, const int2e* __restrict__ esort,
        const float* __restrict__ dis, const float* __restrict__ W3,
        const float* __restrict__ b3, float* __restrict__ out, int n) {
    int v = (int)((blockIdx.x * blockDim.x + threadIdx.x) >> 6);
    int lane = threadIdx.x & 63;
    if (v >= n) return;
    int half = lane >> 5, j = lane & 31;
    float a0 = 0.f, a1 = 0.f, a2 = 0.f, a3 = 0.f;
    gather_accum2(xw, esort, dis, v, half, j, row_ptr[v], row_ptr[v + 1], a0, a1, a2, a3);
    // lane covers W3 rows (4j + 2*half, 4j + 2*half + 1)
    const float* w0 = W3 + (size_t)(j * 4 + half * 2) * 10;
    float hA = half ? a2 : a0;
    float hB = half ? a3 : a1;
    float p[10];
#pragma unroll
    for (int c = 0; c < 10; ++c) p[c] = hA * w0[c] + hB * w0[10 + c];
#pragma unroll
    for (int c = 0; c < 10; ++c) {
#pragma unroll
        for (int d = 1; d < 64; d <<= 1) p[c] += __shfl_xor(p[c], d);
    }
#pragma unroll
    for (int c = 0; c < 10; ++c) p[c] += b3[c];
    float m = p[0];
#pragma unroll
    for (int c = 1; c < 10; ++c) m = fmaxf(m, p[c]);
    float ssum = 0.f;
#pragma unroll
    for (int c = 0; c < 10; ++c) ssum += __expf(p[c] - m);
    float ls = __logf(ssum);
    if (lane < 10) out[(size_t)v * 10 + lane] = p[lane] - m - ls;
}

extern "C" void kernel_launch(void* const* d_in, const int* in_sizes, int n_in,
                              void* d_out, int out_size, void* d_ws, size_t ws_size,
                              hipStream_t stream) {
    const float* x  = (const float*)d_in[0];
    const int*   ei = (const int*)d_in[1];   // [2][E] int32
    const float* W1 = (const float*)d_in[2];
    const float* b1 = (const float*)d_in[3];
    const float* W2 = (const float*)d_in[4];
    const float* b2 = (const float*)d_in[5];
    const float* W3 = (const float*)d_in[6];
    const float* b3 = (const float*)d_in[7];
    int N = in_sizes[0] / 128;
    int E = in_sizes[1] / 2;
    int NB = (N + 1023) / 1024;   // 49 for N=50000 (must be <= 64)

    char* ws = (char*)d_ws;
    size_t off = 0;
    auto alloc = [&](size_t bytes) -> char* {
        char* p = ws + off;
        off = (off + bytes + 255) & ~(size_t)255;
        return p;
    };
    int*   cnt     = (int*)alloc((size_t)N * 4);
    int*   fillc   = (int*)alloc((size_t)N * 4);
    int*   row_ptr = (int*)alloc(((size_t)N + 1) * 4);
    float* dis     = (float*)alloc((size_t)N * 4);
    int*   bsum    = (int*)alloc(64 * 4);
    u16*   Wt1     = (u16*)alloc(128 * 128 * 2);
    u16*   Wt2     = (u16*)alloc(128 * 128 * 2);
    int2e* esort   = (int2e*)alloc((size_t)E * 8);
    uint*  bufA    = (uint*)alloc((size_t)N * 64 * 4);   // bf16x2 packed [N][64]
    uint*  bufB    = (uint*)alloc((size_t)N * 64 * 4);   // bf16x2 packed [N][64]

    // cnt and fillc are adjacent in ws: one memset covers both.
    (void)hipMemsetAsync(cnt, 0, (size_t)((char*)fillc - (char*)cnt) + (size_t)N * 4, stream);

    // --- graph preprocessing (shared by all 3 layers) + weight transposes ---
    count_kernel<<<1024, 256, 0, stream>>>(ei, E, cnt);
    wt_kernel<<<2, 256, 0, stream>>>(W1, W2, Wt1, Wt2);
    scan_partial<<<NB, 256, 0, stream>>>(cnt, bsum, dis, N);
    scan_final<<<NB, 256, 0, stream>>>(cnt, bsum, row_ptr, NB, N);
    fill_kernel<<<1024, 256, 0, stream>>>(ei, E, row_ptr, fillc, dis, esort);

    int gemm_grid = (N + 63) / 64;
    // --- layer 1: relu(Agg(x@W1) + b1) ---
    gemm_mfma<float><<<gemm_grid, 256, 0, stream>>>(x, Wt1, (u16*)bufA, N);
    agg_kernel<2><<<(N + 3) / 4, 256, 0, stream>>>(bufA, row_ptr, esort, dis, b1, bufB, N);
    // --- layer 2: Agg(h1@W2) + b2 ---
    gemm_mfma<u16><<<gemm_grid, 256, 0, stream>>>((const u16*)bufB, Wt2, (u16*)bufA, N);
    agg_kernel<1><<<(N + 3) / 4, 256, 0, stream>>>(bufA, row_ptr, esort, dis, b2, bufB, N);
    // --- layer 3 fused: log_softmax(Agg(h2) @ W3 + b3) ---
    agg_out_kernel<<<(N + 3) / 4, 256, 0, stream>>>(bufB, row_ptr, esort, dis, W3, b3,
                                                    (float*)d_out, N);
}

// Round 9
// 235.158 us; speedup vs baseline: 1.0827x; 1.0827x over previous
//
#include <hip/hip_runtime.h>
#include <cstdint>
#include <cstddef>

// ---------------------------------------------------------------------------
// GCN: 3 layers, shared graph.
//   - Agg passes are at a COMPULSORY L2-fill floor (~82MB/pass @ ~1.7TB/s
//     random-fill = ~48us): random graph, every XCD first-touches ~86% of the
//     12.8MB bf16 feature table. R7 (pairing) and R8 (16-deep MLP) both flat.
//     Gather uses the R6 full-wave form (fastest measured: 2 lines/instr).
//   - GEMM2 ELIMINATED by linearity:
//       Agg(Agg(h1)@W2+b2)@W3+b3 = Agg2(h1)@(W2@W3) + s*(b2@W3) + b3,
//     s[v] = row-sum of normalized adjacency, accumulated free in the last
//     gather. W23=W2@W3 (128x10), b23=b2@W3 precomputed in wt_kernel.
//   - Features between stages packed bf16x2 (halves gather bytes).
//   - GEMM1: bf16 MFMA 16x16x32, C via LDS round-trip (16B coalesced stores).
// ---------------------------------------------------------------------------

typedef unsigned int uint;
typedef unsigned short u16;
typedef uint  uint4e  __attribute__((ext_vector_type(4)));
typedef float float4e __attribute__((ext_vector_type(4)));
typedef uint  uint2e  __attribute__((ext_vector_type(2)));
typedef int   int2e   __attribute__((ext_vector_type(2)));
typedef int   int4e   __attribute__((ext_vector_type(4)));
using bf16x8 = __attribute__((ext_vector_type(8))) short;
using f32x4  = __attribute__((ext_vector_type(4))) float;

__device__ __forceinline__ float bf_lo(uint v) { return __uint_as_float(v << 16); }
__device__ __forceinline__ float bf_hi(uint v) { return __uint_as_float(v & 0xffff0000u); }
__device__ __forceinline__ u16 bf16_1(float a) {
    uint ua = __float_as_uint(a);
    ua = (ua + 0x7fffu + ((ua >> 16) & 1u)) >> 16;          // RNE
    return (u16)ua;
}
__device__ __forceinline__ uint pack_bf2(float a, float b) {
    return (uint)bf16_1(a) | ((uint)bf16_1(b) << 16);
}

__global__ void count_kernel(const int* __restrict__ ei, int E, int* __restrict__ cnt) {
    int i = blockIdx.x * blockDim.x + threadIdx.x;
    int stride = gridDim.x * blockDim.x;
    int nG = E >> 2;
    for (int g = i; g < nG; g += stride) {
        int4e d = *reinterpret_cast<const int4e*>(ei + E + g * 4);
        atomicAdd(&cnt[d.x], 1);
        atomicAdd(&cnt[d.y], 1);
        atomicAdd(&cnt[d.z], 1);
        atomicAdd(&cnt[d.w], 1);
    }
    for (int e = nG * 4 + i; e < E; e += stride) atomicAdd(&cnt[ei[E + e]], 1);
}

// Pass 1: per-block (1024 elems) totals; also computes dis = rsqrt(deg+1).
__global__ __launch_bounds__(256) void scan_partial(const int* __restrict__ cnt,
        int* __restrict__ bsum, float* __restrict__ dis, int n) {
    __shared__ int red[256];
    int b = blockIdx.x, tid = threadIdx.x;
    int base = b * 1024 + tid * 4;
    int4 v = make_int4(0, 0, 0, 0);
    if (base + 4 <= n) {
        v = *reinterpret_cast<const int4*>(cnt + base);
    } else {
        if (base + 0 < n) v.x = cnt[base + 0];
        if (base + 1 < n) v.y = cnt[base + 1];
        if (base + 2 < n) v.z = cnt[base + 2];
    }
    if (base + 0 < n) dis[base + 0] = rsqrtf((float)(v.x + 1));
    if (base + 1 < n) dis[base + 1] = rsqrtf((float)(v.y + 1));
    if (base + 2 < n) dis[base + 2] = rsqrtf((float)(v.z + 1));
    if (base + 3 < n) dis[base + 3] = rsqrtf((float)(v.w + 1));
    red[tid] = v.x + v.y + v.z + v.w;
    __syncthreads();
    for (int d = 128; d > 0; d >>= 1) {
        if (tid < d) red[tid] += red[tid + d];
        __syncthreads();
    }
    if (tid == 0) bsum[b] = red[0];
}

// Pass 2: wave 0 redundantly scans block sums for this block's offset, then
// block-local exclusive scan + offset -> row_ptr.
__global__ __launch_bounds__(256) void scan_final(const int* __restrict__ cnt,
        const int* __restrict__ bsum, int* __restrict__ row_ptr, int nb, int n) {
    __shared__ int red[256];
    __shared__ int sh_boff;
    int b = blockIdx.x, tid = threadIdx.x;
    if (tid < 64) {
        int s = (tid < nb) ? bsum[tid] : 0;
        int v = s;
        for (int d = 1; d < 64; d <<= 1) {
            int t = __shfl_up(v, d);
            if (tid >= d) v += t;
        }
        if (tid == b) sh_boff = v - s;                 // exclusive offset of this block
        if (b == 0 && tid == 63) row_ptr[n] = v;       // grand total
    }
    int base = b * 1024 + tid * 4;
    int4 v = make_int4(0, 0, 0, 0);
    if (base + 4 <= n) {
        v = *reinterpret_cast<const int4*>(cnt + base);
    } else {
        if (base + 0 < n) v.x = cnt[base + 0];
        if (base + 1 < n) v.y = cnt[base + 1];
        if (base + 2 < n) v.z = cnt[base + 2];
    }
    int s = v.x + v.y + v.z + v.w;
    red[tid] = s;
    __syncthreads();
    for (int d = 1; d < 256; d <<= 1) {
        int t = (tid >= d) ? red[tid - d] : 0;
        __syncthreads();
        red[tid] += t;
        __syncthreads();
    }
    int off = sh_boff + red[tid] - s;
    if (base + 0 < n) { row_ptr[base + 0] = off; off += v.x; }
    if (base + 1 < n) { row_ptr[base + 1] = off; off += v.y; }
    if (base + 2 < n) { row_ptr[base + 2] = off; off += v.z; }
    if (base + 3 < n) { row_ptr[base + 3] = off; }
}

__global__ void fill_kernel(const int* __restrict__ ei, int E,
                            const int* __restrict__ row_ptr, int* __restrict__ fillc,
                            const float* __restrict__ dis, int2e* __restrict__ esort) {
    int i = blockIdx.x * blockDim.x + threadIdx.x;
    int stride = gridDim.x * blockDim.x;
    int nG = E >> 2;
    for (int g = i; g < nG; g += stride) {
        int4e s4 = *reinterpret_cast<const int4e*>(ei + g * 4);
        int4e d4 = *reinterpret_cast<const int4e*>(ei + E + g * 4);
#pragma unroll
        for (int k = 0; k < 4; ++k) {
            int s = k == 0 ? s4.x : k == 1 ? s4.y : k == 2 ? s4.z : s4.w;
            int d = k == 0 ? d4.x : k == 1 ? d4.y : k == 2 ? d4.z : d4.w;
            int pos = row_ptr[d] + atomicAdd(&fillc[d], 1);
            int2e pkt;
            pkt.x = s;
            pkt.y = __float_as_int(dis[s] * dis[d]);
            esort[pos] = pkt;
        }
    }
    for (int e = nG * 4 + i; e < E; e += stride) {
        int s = ei[e];
        int d = ei[E + e];
        int pos = row_ptr[d] + atomicAdd(&fillc[d], 1);
        int2e pkt;
        pkt.x = s;
        pkt.y = __float_as_int(dis[s] * dis[d]);
        esort[pos] = pkt;
    }
}

// Weight prep. Block 0: Wt1[c][k] = bf16(W1[k][c]).
// Block 1: W23 = W2 @ W3 (128x10 f32), b23 = b2 @ W3 (10 f32).
__global__ __launch_bounds__(256) void wt_kernel(const float* __restrict__ W1,
        const float* __restrict__ W2, const float* __restrict__ W3,
        const float* __restrict__ b2,
        u16* __restrict__ Wt1, float* __restrict__ W23, float* __restrict__ b23) {
    int tid = threadIdx.x;
    if (blockIdx.x == 0) {
        for (int i = 0; i < 64; ++i) {
            int idx = tid + i * 256;          // 16384 = 128*128
            int k = idx >> 7, c = idx & 127;
            Wt1[c * 128 + k] = bf16_1(W1[idx]);
        }
    } else {
        __shared__ float w3s[1280];
        for (int i = tid; i < 1280; i += 256) w3s[i] = W3[i];
        __syncthreads();
#pragma unroll
        for (int i = 0; i < 5; ++i) {
            int idx = tid * 5 + i;            // 1280 outputs
            int k = idx / 10, c = idx % 10;
            float acc = 0.f;
            for (int j = 0; j < 128; ++j) acc += W2[k * 128 + j] * w3s[j * 10 + c];
            W23[idx] = acc;
        }
        if (tid < 10) {
            float acc = 0.f;
            for (int j = 0; j < 128; ++j) acc += b2[j] * w3s[j * 10 + tid];
            b23[tid] = acc;
        }
    }
}

// out u16[n][128] = bf16( A[n][128] @ W ),  W given as Wt bf16 [col][k].
// C is written via LDS round-trip -> fully coalesced 16B stores.
__global__ __launch_bounds__(256) void gemm_mfma(const float* __restrict__ A,
        const u16* __restrict__ Wt, u16* __restrict__ out, int n) {
    constexpr int LDA = 136;                 // 128 + 8 pad (bf16) -> 2-way LDS only
    __shared__ u16 as[64 * LDA];
    int tid = threadIdx.x;
    int wave = tid >> 6, lane = tid & 63;
    int row0 = blockIdx.x * 64;
    int l16 = lane & 15;
    int krow = (lane >> 4) * 8;              // k-octet within 32-wide K block

#pragma unroll
    for (int i = 0; i < 8; ++i) {
        int idx = tid + i * 256;             // 2048 quads of 4 f32
        int r = idx >> 5;
        int q = (idx & 31) * 4;
        float4e v = {0.f, 0.f, 0.f, 0.f};
        if (row0 + r < n)
            v = *reinterpret_cast<const float4e*>(A + (size_t)(row0 + r) * 128 + q);
        uint2e p;
        p.x = pack_bf2(v.x, v.y);
        p.y = pack_bf2(v.z, v.w);
        *reinterpret_cast<uint2e*>(&as[r * LDA + q]) = p;
    }

    bf16x8 b[2][4];
#pragma unroll
    for (int n2 = 0; n2 < 2; ++n2)
#pragma unroll
        for (int kb = 0; kb < 4; ++kb)
            b[n2][kb] = *reinterpret_cast<const bf16x8*>(
                Wt + (size_t)(wave * 32 + n2 * 16 + l16) * 128 + kb * 32 + krow);

    __syncthreads();

    f32x4 acc[4][2] = {};
#pragma unroll
    for (int m = 0; m < 4; ++m) {
#pragma unroll
        for (int kb = 0; kb < 4; ++kb) {
            bf16x8 a = *reinterpret_cast<const bf16x8*>(
                &as[(m * 16 + l16) * LDA + kb * 32 + krow]);
#pragma unroll
            for (int n2 = 0; n2 < 2; ++n2)
                acc[m][n2] = __builtin_amdgcn_mfma_f32_16x16x32_bf16(a, b[n2][kb], acc[m][n2], 0, 0, 0);
        }
    }

    // ---- C via LDS: bf16 into cs[row][col] (stride 128), then 16B stores ----
    __syncthreads();                         // as[] reuse
    u16* cs = as;
#pragma unroll
    for (int m = 0; m < 4; ++m) {
        int rb = m * 16 + (lane >> 4) * 4;
#pragma unroll
        for (int n2 = 0; n2 < 2; ++n2) {
            int col = wave * 32 + n2 * 16 + l16;
#pragma unroll
            for (int r = 0; r < 4; ++r)
                cs[(rb + r) * 128 + col] = bf16_1(acc[m][n2][r]);
        }
    }
    __syncthreads();
#pragma unroll
    for (int i = 0; i < 4; ++i) {
        int idx = tid + i * 256;             // 1024 octs: row=idx>>4, oct=(idx&15)
        int r = idx >> 4;
        int q = (idx & 15) * 8;
        if (row0 + r < n)
            *reinterpret_cast<uint4e*>(out + (size_t)(row0 + r) * 128 + q) =
                *reinterpret_cast<const uint4e*>(&cs[r * 128 + q]);
    }
}

// Full-wave gather (R6 form, fastest measured): lane owns dims 2*lane..2*lane+1,
// 8 edges in flight. Also accumulates sw = sum of norm weights (= s[v], same
// value in every lane; ~free, needed by the fused final layer).
__device__ __forceinline__ void gather_accum(const uint* __restrict__ xw,
        const int2e* __restrict__ esort, const float* __restrict__ dis,
        int v, int lane, int beg, int end, float& ax, float& ay, float& sw) {
    int e = beg;
    for (; e + 7 < end; e += 8) {
        int2e ed[8];
        uint vv[8];
#pragma unroll
        for (int j = 0; j < 8; ++j) ed[j] = esort[e + j];
#pragma unroll
        for (int j = 0; j < 8; ++j) vv[j] = xw[(size_t)ed[j].x * 64 + lane];
#pragma unroll
        for (int j = 0; j < 8; ++j) {
            float w = __int_as_float(ed[j].y);
            ax += w * bf_lo(vv[j]);
            ay += w * bf_hi(vv[j]);
            sw += w;
        }
    }
    for (; e + 1 < end; e += 2) {
        int2e e0 = esort[e];
        int2e e1 = esort[e + 1];
        uint v0 = xw[(size_t)e0.x * 64 + lane];
        uint v1 = xw[(size_t)e1.x * 64 + lane];
        float w0 = __int_as_float(e0.y), w1 = __int_as_float(e1.y);
        ax += w0 * bf_lo(v0); ay += w0 * bf_hi(v0);
        ax += w1 * bf_lo(v1); ay += w1 * bf_hi(v1);
        sw += w0 + w1;
    }
    if (e < end) {
        int2e e0 = esort[e];
        uint v0 = xw[(size_t)e0.x * 64 + lane];
        float w0 = __int_as_float(e0.y);
        ax += w0 * bf_lo(v0); ay += w0 * bf_hi(v0);
        sw += w0;
    }
    float dv = dis[v];
    float wv = dv * dv;                            // self-loop norm
    uint vs = xw[(size_t)v * 64 + lane];
    ax += wv * bf_lo(vs); ay += wv * bf_hi(vs);
    sw += wv;
}

// CSR aggregation -> packed bf16. MODE: 0 = plain, 2 = +bias+relu.
template <int MODE>
__global__ __launch_bounds__(256) void agg_kernel(const uint* __restrict__ xw,
        const int* __restrict__ row_ptr, const int2e* __restrict__ esort,
        const float* __restrict__ dis, const float* __restrict__ bias,
        uint* __restrict__ out, int n) {
    int v = (int)((blockIdx.x * blockDim.x + threadIdx.x) >> 6);
    int lane = threadIdx.x & 63;
    if (v >= n) return;
    float ax = 0.f, ay = 0.f, sw = 0.f;
    gather_accum(xw, esort, dis, v, lane, row_ptr[v], row_ptr[v + 1], ax, ay, sw);
    if (MODE >= 1) {
        ax += bias[lane * 2];
        ay += bias[lane * 2 + 1];
    }
    if (MODE == 2) { ax = fmaxf(ax, 0.f); ay = fmaxf(ay, 0.f); }
    out[(size_t)v * 64 + lane] = pack_bf2(ax, ay);
}

// Final fused layer (layers 2+3 collapsed by linearity):
//   out = log_softmax( Agg(g1) @ W23 + s[v]*b23 + b3 ),  W23 = W2@W3.
__global__ __launch_bounds__(256) void agg_out_kernel(const uint* __restrict__ xw,
        const int* __restrict__ row_ptr, const int2e* __restrict__ esort,
        const float* __restrict__ dis, const float* __restrict__ W23,
        const float* __restrict__ b23, const float* __restrict__ b3,
        float* __restrict__ out, int n) {
    int v = (int)((blockIdx.x * blockDim.x + threadIdx.x) >> 6);
    int lane = threadIdx.x & 63;
    if (v >= n) return;
    float ax = 0.f, ay = 0.f, sw = 0.f;
    gather_accum(xw, esort, dis, v, lane, row_ptr[v], row_ptr[v + 1], ax, ay, sw);
    // projection: this lane's 2 rows of W23
    const float* w0 = W23 + (size_t)lane * 20;
    float p[10];
#pragma unroll
    for (int c = 0; c < 10; ++c) p[c] = ax * w0[c] + ay * w0[10 + c];
#pragma unroll
    for (int c = 0; c < 10; ++c) {
#pragma unroll
        for (int d = 1; d < 64; d <<= 1) p[c] += __shfl_xor(p[c], d);
    }
#pragma unroll
    for (int c = 0; c < 10; ++c) p[c] += sw * b23[c] + b3[c];
    float m = p[0];
#pragma unroll
    for (int c = 1; c < 10; ++c) m = fmaxf(m, p[c]);
    float ssum = 0.f;
#pragma unroll
    for (int c = 0; c < 10; ++c) ssum += __expf(p[c] - m);
    float ls = __logf(ssum);
    if (lane < 10) out[(size_t)v * 10 + lane] = p[lane] - m - ls;
}

extern "C" void kernel_launch(void* const* d_in, const int* in_sizes, int n_in,
                              void* d_out, int out_size, void* d_ws, size_t ws_size,
                              hipStream_t stream) {
    const float* x  = (const float*)d_in[0];
    const int*   ei = (const int*)d_in[1];   // [2][E] int32
    const float* W1 = (const float*)d_in[2];
    const float* b1 = (const float*)d_in[3];
    const float* W2 = (const float*)d_in[4];
    const float* b2 = (const float*)d_in[5];
    const float* W3 = (const float*)d_in[6];
    const float* b3 = (const float*)d_in[7];
    int N = in_sizes[0] / 128;
    int E = in_sizes[1] / 2;
    int NB = (N + 1023) / 1024;   // 49 for N=50000 (must be <= 64)

    char* ws = (char*)d_ws;
    size_t off = 0;
    auto alloc = [&](size_t bytes) -> char* {
        char* p = ws + off;
        off = (off + bytes + 255) & ~(size_t)255;
        return p;
    };
    int*   cnt     = (int*)alloc((size_t)N * 4);
    int*   fillc   = (int*)alloc((size_t)N * 4);
    int*   row_ptr = (int*)alloc(((size_t)N + 1) * 4);
    float* dis     = (float*)alloc((size_t)N * 4);
    int*   bsum    = (int*)alloc(64 * 4);
    u16*   Wt1     = (u16*)alloc(128 * 128 * 2);
    float* W23     = (float*)alloc(128 * 10 * 4);
    float* b23     = (float*)alloc(10 * 4);
    int2e* esort   = (int2e*)alloc((size_t)E * 8);
    uint*  bufA    = (uint*)alloc((size_t)N * 64 * 4);   // bf16x2 packed [N][64]
    uint*  bufB    = (uint*)alloc((size_t)N * 64 * 4);   // bf16x2 packed [N][64]

    // cnt and fillc are adjacent in ws: one memset covers both.
    (void)hipMemsetAsync(cnt, 0, (size_t)((char*)fillc - (char*)cnt) + (size_t)N * 4, stream);

    // --- graph preprocessing (shared by all 3 layers) + weight prep ---
    count_kernel<<<1024, 256, 0, stream>>>(ei, E, cnt);
    wt_kernel<<<2, 256, 0, stream>>>(W1, W2, W3, b2, Wt1, W23, b23);
    scan_partial<<<NB, 256, 0, stream>>>(cnt, bsum, dis, N);
    scan_final<<<NB, 256, 0, stream>>>(cnt, bsum, row_ptr, NB, N);
    fill_kernel<<<1024, 256, 0, stream>>>(ei, E, row_ptr, fillc, dis, esort);

    // --- layer 1: h1 = relu(Agg(x@W1) + b1) ---
    gemm_mfma<<<(N + 63) / 64, 256, 0, stream>>>(x, Wt1, (u16*)bufA, N);
    agg_kernel<2><<<(N + 3) / 4, 256, 0, stream>>>(bufA, row_ptr, esort, dis, b1, bufB, N);
    // --- layers 2+3 collapsed: g1 = Agg(h1); out = log_softmax(Agg(g1)@W23 + s*b23 + b3) ---
    agg_kernel<0><<<(N + 3) / 4, 256, 0, stream>>>(bufB, row_ptr, esort, dis, nullptr, bufA, N);
    agg_out_kernel<<<(N + 3) / 4, 256, 0, stream>>>(bufA, row_ptr, esort, dis, W23, b23, b3,
                                                    (float*)d_out, N);
}

// Round 10
// 198.080 us; speedup vs baseline: 1.2854x; 1.1872x over previous
//
#include <hip/hip_runtime.h>
#include <cstdint>
#include <cstddef>

// ---------------------------------------------------------------------------
// GCN: 3 layers, shared graph.
//   - KEY ALGEBRA: only layer 1 has ReLU; everything after is linear, and
//     feature-space projection commutes with aggregation:
//       out = log_softmax( A^2 (h1 W23) + s*(b2W3) + b3 ),  W23 = W2@W3.
//     So project h1 -> 10 dims INSIDE the first (unavoidable) 128-dim gather
//     pass, then run BOTH remaining aggregations in 10-dim f32 space:
//     table = 50k x 40B = 2MB -> L2-RESIDENT per XCD. The ~82MB compulsory
//     fill floor (measured R7-R9) applies only to the one 128-dim pass.
//   - Pass A (big): gather bf16 x@W1 rows, relu(+b1), project via W23
//     butterfly, write z[N][10] f32.
//   - Pass B/C (tiny): 10-dim aggregations, 4 nodes/wave (16-lane groups).
//     Pass C adds s*b23+b3 and log_softmax (width-16 butterflies).
//   - GEMM1: bf16 MFMA 16x16x32, C via LDS round-trip (16B stores).
// ---------------------------------------------------------------------------

typedef unsigned int uint;
typedef unsigned short u16;
typedef uint  uint4e  __attribute__((ext_vector_type(4)));
typedef float float4e __attribute__((ext_vector_type(4)));
typedef uint  uint2e  __attribute__((ext_vector_type(2)));
typedef int   int2e   __attribute__((ext_vector_type(2)));
typedef int   int4e   __attribute__((ext_vector_type(4)));
using bf16x8 = __attribute__((ext_vector_type(8))) short;
using f32x4  = __attribute__((ext_vector_type(4))) float;

__device__ __forceinline__ float bf_lo(uint v) { return __uint_as_float(v << 16); }
__device__ __forceinline__ float bf_hi(uint v) { return __uint_as_float(v & 0xffff0000u); }
__device__ __forceinline__ u16 bf16_1(float a) {
    uint ua = __float_as_uint(a);
    ua = (ua + 0x7fffu + ((ua >> 16) & 1u)) >> 16;          // RNE
    return (u16)ua;
}
__device__ __forceinline__ uint pack_bf2(float a, float b) {
    return (uint)bf16_1(a) | ((uint)bf16_1(b) << 16);
}

__global__ void count_kernel(const int* __restrict__ ei, int E, int* __restrict__ cnt) {
    int i = blockIdx.x * blockDim.x + threadIdx.x;
    int stride = gridDim.x * blockDim.x;
    int nG = E >> 2;
    for (int g = i; g < nG; g += stride) {
        int4e d = *reinterpret_cast<const int4e*>(ei + E + g * 4);
        atomicAdd(&cnt[d.x], 1);
        atomicAdd(&cnt[d.y], 1);
        atomicAdd(&cnt[d.z], 1);
        atomicAdd(&cnt[d.w], 1);
    }
    for (int e = nG * 4 + i; e < E; e += stride) atomicAdd(&cnt[ei[E + e]], 1);
}

// Pass 1: per-block (1024 elems) totals; also computes dis = rsqrt(deg+1).
__global__ __launch_bounds__(256) void scan_partial(const int* __restrict__ cnt,
        int* __restrict__ bsum, float* __restrict__ dis, int n) {
    __shared__ int red[256];
    int b = blockIdx.x, tid = threadIdx.x;
    int base = b * 1024 + tid * 4;
    int4 v = make_int4(0, 0, 0, 0);
    if (base + 4 <= n) {
        v = *reinterpret_cast<const int4*>(cnt + base);
    } else {
        if (base + 0 < n) v.x = cnt[base + 0];
        if (base + 1 < n) v.y = cnt[base + 1];
        if (base + 2 < n) v.z = cnt[base + 2];
    }
    if (base + 0 < n) dis[base + 0] = rsqrtf((float)(v.x + 1));
    if (base + 1 < n) dis[base + 1] = rsqrtf((float)(v.y + 1));
    if (base + 2 < n) dis[base + 2] = rsqrtf((float)(v.z + 1));
    if (base + 3 < n) dis[base + 3] = rsqrtf((float)(v.w + 1));
    red[tid] = v.x + v.y + v.z + v.w;
    __syncthreads();
    for (int d = 128; d > 0; d >>= 1) {
        if (tid < d) red[tid] += red[tid + d];
        __syncthreads();
    }
    if (tid == 0) bsum[b] = red[0];
}

// Pass 2: wave 0 redundantly scans block sums for this block's offset, then
// block-local exclusive scan + offset -> row_ptr.
__global__ __launch_bounds__(256) void scan_final(const int* __restrict__ cnt,
        const int* __restrict__ bsum, int* __restrict__ row_ptr, int nb, int n) {
    __shared__ int red[256];
    __shared__ int sh_boff;
    int b = blockIdx.x, tid = threadIdx.x;
    if (tid < 64) {
        int s = (tid < nb) ? bsum[tid] : 0;
        int v = s;
        for (int d = 1; d < 64; d <<= 1) {
            int t = __shfl_up(v, d);
            if (tid >= d) v += t;
        }
        if (tid == b) sh_boff = v - s;                 // exclusive offset of this block
        if (b == 0 && tid == 63) row_ptr[n] = v;       // grand total
    }
    int base = b * 1024 + tid * 4;
    int4 v = make_int4(0, 0, 0, 0);
    if (base + 4 <= n) {
        v = *reinterpret_cast<const int4*>(cnt + base);
    } else {
        if (base + 0 < n) v.x = cnt[base + 0];
        if (base + 1 < n) v.y = cnt[base + 1];
        if (base + 2 < n) v.z = cnt[base + 2];
    }
    int s = v.x + v.y + v.z + v.w;
    red[tid] = s;
    __syncthreads();
    for (int d = 1; d < 256; d <<= 1) {
        int t = (tid >= d) ? red[tid - d] : 0;
        __syncthreads();
        red[tid] += t;
        __syncthreads();
    }
    int off = sh_boff + red[tid] - s;
    if (base + 0 < n) { row_ptr[base + 0] = off; off += v.x; }
    if (base + 1 < n) { row_ptr[base + 1] = off; off += v.y; }
    if (base + 2 < n) { row_ptr[base + 2] = off; off += v.z; }
    if (base + 3 < n) { row_ptr[base + 3] = off; }
}

__global__ void fill_kernel(const int* __restrict__ ei, int E,
                            const int* __restrict__ row_ptr, int* __restrict__ fillc,
                            const float* __restrict__ dis, int2e* __restrict__ esort) {
    int i = blockIdx.x * blockDim.x + threadIdx.x;
    int stride = gridDim.x * blockDim.x;
    int nG = E >> 2;
    for (int g = i; g < nG; g += stride) {
        int4e s4 = *reinterpret_cast<const int4e*>(ei + g * 4);
        int4e d4 = *reinterpret_cast<const int4e*>(ei + E + g * 4);
#pragma unroll
        for (int k = 0; k < 4; ++k) {
            int s = k == 0 ? s4.x : k == 1 ? s4.y : k == 2 ? s4.z : s4.w;
            int d = k == 0 ? d4.x : k == 1 ? d4.y : k == 2 ? d4.z : d4.w;
            int pos = row_ptr[d] + atomicAdd(&fillc[d], 1);
            int2e pkt;
            pkt.x = s;
            pkt.y = __float_as_int(dis[s] * dis[d]);
            esort[pos] = pkt;
        }
    }
    for (int e = nG * 4 + i; e < E; e += stride) {
        int s = ei[e];
        int d = ei[E + e];
        int pos = row_ptr[d] + atomicAdd(&fillc[d], 1);
        int2e pkt;
        pkt.x = s;
        pkt.y = __float_as_int(dis[s] * dis[d]);
        esort[pos] = pkt;
    }
}

// Weight prep. Block 0: Wt1[c][k] = bf16(W1[k][c]).
// Block 1: W23 = W2 @ W3 (128x10 f32), b23 = b2 @ W3 (10 f32).
__global__ __launch_bounds__(256) void wt_kernel(const float* __restrict__ W1,
        const float* __restrict__ W2, const float* __restrict__ W3,
        const float* __restrict__ b2,
        u16* __restrict__ Wt1, float* __restrict__ W23, float* __restrict__ b23) {
    int tid = threadIdx.x;
    if (blockIdx.x == 0) {
        for (int i = 0; i < 64; ++i) {
            int idx = tid + i * 256;          // 16384 = 128*128
            int k = idx >> 7, c = idx & 127;
            Wt1[c * 128 + k] = bf16_1(W1[idx]);
        }
    } else {
        __shared__ float w3s[1280];
        for (int i = tid; i < 1280; i += 256) w3s[i] = W3[i];
        __syncthreads();
#pragma unroll
        for (int i = 0; i < 5; ++i) {
            int idx = tid * 5 + i;            // 1280 outputs
            int k = idx / 10, c = idx % 10;
            float acc = 0.f;
            for (int j = 0; j < 128; ++j) acc += W2[k * 128 + j] * w3s[j * 10 + c];
            W23[idx] = acc;
        }
        if (tid < 10) {
            float acc = 0.f;
            for (int j = 0; j < 128; ++j) acc += b2[j] * w3s[j * 10 + tid];
            b23[tid] = acc;
        }
    }
}

// out u16[n][128] = bf16( A[n][128] @ W ),  W given as Wt bf16 [col][k].
// C is written via LDS round-trip -> fully coalesced 16B stores.
__global__ __launch_bounds__(256) void gemm_mfma(const float* __restrict__ A,
        const u16* __restrict__ Wt, u16* __restrict__ out, int n) {
    constexpr int LDA = 136;                 // 128 + 8 pad (bf16) -> 2-way LDS only
    __shared__ u16 as[64 * LDA];
    int tid = threadIdx.x;
    int wave = tid >> 6, lane = tid & 63;
    int row0 = blockIdx.x * 64;
    int l16 = lane & 15;
    int krow = (lane >> 4) * 8;              // k-octet within 32-wide K block

#pragma unroll
    for (int i = 0; i < 8; ++i) {
        int idx = tid + i * 256;             // 2048 quads of 4 f32
        int r = idx >> 5;
        int q = (idx & 31) * 4;
        float4e v = {0.f, 0.f, 0.f, 0.f};
        if (row0 + r < n)
            v = *reinterpret_cast<const float4e*>(A + (size_t)(row0 + r) * 128 + q);
        uint2e p;
        p.x = pack_bf2(v.x, v.y);
        p.y = pack_bf2(v.z, v.w);
        *reinterpret_cast<uint2e*>(&as[r * LDA + q]) = p;
    }

    bf16x8 b[2][4];
#pragma unroll
    for (int n2 = 0; n2 < 2; ++n2)
#pragma unroll
        for (int kb = 0; kb < 4; ++kb)
            b[n2][kb] = *reinterpret_cast<const bf16x8*>(
                Wt + (size_t)(wave * 32 + n2 * 16 + l16) * 128 + kb * 32 + krow);

    __syncthreads();

    f32x4 acc[4][2] = {};
#pragma unroll
    for (int m = 0; m < 4; ++m) {
#pragma unroll
        for (int kb = 0; kb < 4; ++kb) {
            bf16x8 a = *reinterpret_cast<const bf16x8*>(
                &as[(m * 16 + l16) * LDA + kb * 32 + krow]);
#pragma unroll
            for (int n2 = 0; n2 < 2; ++n2)
                acc[m][n2] = __builtin_amdgcn_mfma_f32_16x16x32_bf16(a, b[n2][kb], acc[m][n2], 0, 0, 0);
        }
    }

    // ---- C via LDS: bf16 into cs[row][col] (stride 128), then 16B stores ----
    __syncthreads();                         // as[] reuse
    u16* cs = as;
#pragma unroll
    for (int m = 0; m < 4; ++m) {
        int rb = m * 16 + (lane >> 4) * 4;
#pragma unroll
        for (int n2 = 0; n2 < 2; ++n2) {
            int col = wave * 32 + n2 * 16 + l16;
#pragma unroll
            for (int r = 0; r < 4; ++r)
                cs[(rb + r) * 128 + col] = bf16_1(acc[m][n2][r]);
        }
    }
    __syncthreads();
#pragma unroll
    for (int i = 0; i < 4; ++i) {
        int idx = tid + i * 256;             // 1024 octs: row=idx>>4, oct=(idx&15)
        int r = idx >> 4;
        int q = (idx & 15) * 8;
        if (row0 + r < n)
            *reinterpret_cast<uint4e*>(out + (size_t)(row0 + r) * 128 + q) =
                *reinterpret_cast<const uint4e*>(&cs[r * 128 + q]);
    }
}

// Full-wave gather (R6 form): lane owns dims 2*lane..2*lane+1, 8 edges in flight.
__device__ __forceinline__ void gather_accum(const uint* __restrict__ xw,
        const int2e* __restrict__ esort, const float* __restrict__ dis,
        int v, int lane, int beg, int end, float& ax, float& ay) {
    int e = beg;
    for (; e + 7 < end; e += 8) {
        int2e ed[8];
        uint vv[8];
#pragma unroll
        for (int j = 0; j < 8; ++j) ed[j] = esort[e + j];
#pragma unroll
        for (int j = 0; j < 8; ++j) vv[j] = xw[(size_t)ed[j].x * 64 + lane];
#pragma unroll
        for (int j = 0; j < 8; ++j) {
            float w = __int_as_float(ed[j].y);
            ax += w * bf_lo(vv[j]);
            ay += w * bf_hi(vv[j]);
        }
    }
    for (; e + 1 < end; e += 2) {
        int2e e0 = esort[e];
        int2e e1 = esort[e + 1];
        uint v0 = xw[(size_t)e0.x * 64 + lane];
        uint v1 = xw[(size_t)e1.x * 64 + lane];
        float w0 = __int_as_float(e0.y), w1 = __int_as_float(e1.y);
        ax += w0 * bf_lo(v0); ay += w0 * bf_hi(v0);
        ax += w1 * bf_lo(v1); ay += w1 * bf_hi(v1);
    }
    if (e < end) {
        int2e e0 = esort[e];
        uint v0 = xw[(size_t)e0.x * 64 + lane];
        float w0 = __int_as_float(e0.y);
        ax += w0 * bf_lo(v0); ay += w0 * bf_hi(v0);
    }
    float dv = dis[v];
    float wv = dv * dv;                            // self-loop norm
    uint vs = xw[(size_t)v * 64 + lane];
    ax += wv * bf_lo(vs); ay += wv * bf_hi(vs);
}

// Pass A: z[v][0..9] = relu(Agg(x@W1)[v] + b1) @ W23   (the one big gather).
__global__ __launch_bounds__(256) void agg_proj_kernel(const uint* __restrict__ xw,
        const int* __restrict__ row_ptr, const int2e* __restrict__ esort,
        const float* __restrict__ dis, const float* __restrict__ b1,
        const float* __restrict__ W23, float* __restrict__ z, int n) {
    int v = (int)((blockIdx.x * blockDim.x + threadIdx.x) >> 6);
    int lane = threadIdx.x & 63;
    if (v >= n) return;
    float ax = 0.f, ay = 0.f;
    gather_accum(xw, esort, dis, v, lane, row_ptr[v], row_ptr[v + 1], ax, ay);
    ax = fmaxf(ax + b1[lane * 2], 0.f);
    ay = fmaxf(ay + b1[lane * 2 + 1], 0.f);
    const float* w0 = W23 + (size_t)lane * 20;     // this lane's 2 rows of W23
    float p[10];
#pragma unroll
    for (int c = 0; c < 10; ++c) p[c] = ax * w0[c] + ay * w0[10 + c];
#pragma unroll
    for (int c = 0; c < 10; ++c) {
#pragma unroll
        for (int d = 1; d < 64; d <<= 1) p[c] += __shfl_xor(p[c], d);
    }
    if (lane < 10) z[(size_t)v * 10 + lane] = p[lane];
}

// Pass B/C: 10-dim aggregation, 4 nodes per wave (16-lane groups, lanes 0-9
// of each group carry dims). FINAL=0: zout = Agg(zin).
// FINAL=1: out = log_softmax(Agg(zin) + s*b23 + b3).
template <int FINAL>
__global__ __launch_bounds__(256) void agg10_kernel(const float* __restrict__ zin,
        const int* __restrict__ row_ptr, const int2e* __restrict__ esort,
        const float* __restrict__ dis, const float* __restrict__ b23,
        const float* __restrict__ b3, float* __restrict__ zout, int n) {
    int wid = (int)((blockIdx.x * blockDim.x + threadIdx.x) >> 6);
    int lane = threadIdx.x & 63;
    int grp = lane >> 4, gl = lane & 15;
    int v = wid * 4 + grp;
    bool act = (v < n);
    bool dl = (gl < 10);
    int beg = act ? row_ptr[v] : 0;
    int end = act ? row_ptr[v + 1] : 0;
    float acc = 0.f, sw = 0.f;
    int e = beg;
    for (; e + 3 < end; e += 4) {
        int2e e0 = esort[e], e1 = esort[e + 1], e2 = esort[e + 2], e3 = esort[e + 3];
        float z0 = dl ? zin[(size_t)e0.x * 10 + gl] : 0.f;
        float z1 = dl ? zin[(size_t)e1.x * 10 + gl] : 0.f;
        float z2 = dl ? zin[(size_t)e2.x * 10 + gl] : 0.f;
        float z3 = dl ? zin[(size_t)e3.x * 10 + gl] : 0.f;
        float w0 = __int_as_float(e0.y), w1 = __int_as_float(e1.y);
        float w2 = __int_as_float(e2.y), w3 = __int_as_float(e3.y);
        acc += w0 * z0 + w1 * z1 + w2 * z2 + w3 * z3;
        sw += (w0 + w1) + (w2 + w3);
    }
    for (; e < end; ++e) {
        int2e e0 = esort[e];
        float z0 = dl ? zin[(size_t)e0.x * 10 + gl] : 0.f;
        float w0 = __int_as_float(e0.y);
        acc += w0 * z0;
        sw += w0;
    }
    if (act) {
        float dv = dis[v];
        float wv = dv * dv;                        // self-loop
        float zs = dl ? zin[(size_t)v * 10 + gl] : 0.f;
        acc += wv * zs;
        sw += wv;
    }
    if (FINAL == 0) {
        if (act && dl) zout[(size_t)v * 10 + gl] = acc;
    } else {
        float p = acc + (dl ? sw * b23[gl] + b3[gl] : 0.f);
        float m = dl ? p : -3.4e38f;
#pragma unroll
        for (int mask = 1; mask < 16; mask <<= 1) m = fmaxf(m, __shfl_xor(m, mask));
        float s = dl ? __expf(p - m) : 0.f;
#pragma unroll
        for (int mask = 1; mask < 16; mask <<= 1) s += __shfl_xor(s, mask);
        float ls = __logf(s);
        if (act && dl) zout[(size_t)v * 10 + gl] = p - m - ls;
    }
}

extern "C" void kernel_launch(void* const* d_in, const int* in_sizes, int n_in,
                              void* d_out, int out_size, void* d_ws, size_t ws_size,
                              hipStream_t stream) {
    const float* x  = (const float*)d_in[0];
    const int*   ei = (const int*)d_in[1];   // [2][E] int32
    const float* W1 = (const float*)d_in[2];
    const float* b1 = (const float*)d_in[3];
    const float* W2 = (const float*)d_in[4];
    const float* b2 = (const float*)d_in[5];
    const float* W3 = (const float*)d_in[6];
    const float* b3 = (const float*)d_in[7];
    int N = in_sizes[0] / 128;
    int E = in_sizes[1] / 2;
    int NB = (N + 1023) / 1024;   // 49 for N=50000 (must be <= 64)

    char* ws = (char*)d_ws;
    size_t off = 0;
    auto alloc = [&](size_t bytes) -> char* {
        char* p = ws + off;
        off = (off + bytes + 255) & ~(size_t)255;
        return p;
    };
    int*   cnt     = (int*)alloc((size_t)N * 4);
    int*   fillc   = (int*)alloc((size_t)N * 4);
    int*   row_ptr = (int*)alloc(((size_t)N + 1) * 4);
    float* dis     = (float*)alloc((size_t)N * 4);
    int*   bsum    = (int*)alloc(64 * 4);
    u16*   Wt1     = (u16*)alloc(128 * 128 * 2);
    float* W23     = (float*)alloc(128 * 10 * 4);
    float* b23     = (float*)alloc(10 * 4);
    int2e* esort   = (int2e*)alloc((size_t)E * 8);
    uint*  bufA    = (uint*)alloc((size_t)N * 64 * 4);   // bf16x2 packed x@W1
    float* z       = (float*)alloc((size_t)N * 10 * 4);  // h1@W23  (2MB, L2-fits)
    float* z2      = (float*)alloc((size_t)N * 10 * 4);  // Agg(z)

    // cnt and fillc are adjacent in ws: one memset covers both.
    (void)hipMemsetAsync(cnt, 0, (size_t)((char*)fillc - (char*)cnt) + (size_t)N * 4, stream);

    // --- graph preprocessing (shared by all 3 layers) + weight prep ---
    count_kernel<<<1024, 256, 0, stream>>>(ei, E, cnt);
    wt_kernel<<<2, 256, 0, stream>>>(W1, W2, W3, b2, Wt1, W23, b23);
    scan_partial<<<NB, 256, 0, stream>>>(cnt, bsum, dis, N);
    scan_final<<<NB, 256, 0, stream>>>(cnt, bsum, row_ptr, NB, N);
    fill_kernel<<<1024, 256, 0, stream>>>(ei, E, row_ptr, fillc, dis, esort);

    // --- layer 1 GEMM + the single 128-dim gather fused with projection ---
    gemm_mfma<<<(N + 63) / 64, 256, 0, stream>>>(x, Wt1, (u16*)bufA, N);
    agg_proj_kernel<<<(N + 3) / 4, 256, 0, stream>>>(bufA, row_ptr, esort, dis, b1, W23, z, N);
    // --- layers 2+3: two 10-dim aggregations (L2-resident table) ---
    agg10_kernel<0><<<(N + 15) / 16, 256, 0, stream>>>(z, row_ptr, esort, dis, nullptr, nullptr, z2, N);
    agg10_kernel<1><<<(N + 15) / 16, 256, 0, stream>>>(z2, row_ptr, esort, dis, b23, b3, (float*)d_out, N);
}

// Round 11
// 188.530 us; speedup vs baseline: 1.3505x; 1.0507x over previous
//
#include <hip/hip_runtime.h>
#include <cstdint>
#include <cstddef>

// ---------------------------------------------------------------------------
// GCN: 3 layers, shared graph.
//   - Algebra: only layer 1 has ReLU; projection commutes with aggregation:
//       out = log_softmax( A^2 (relu(A xW1 + b1) W23) + s*(b2W3) + b3 ).
//     One 128-dim gather (compulsory L2-fill floor: 82MB @ ~1.7TB/s = 48us,
//     invariant across R7-R10 falsifications), then 10-dim f32 space (2MB,
//     L2-resident).
//   - Serialization cuts (R11): gemm fused into fill (independent block
//     ranges co-execute); wt fused into count; fillc eliminated via
//     count-DOWN fill (atomicSub on cnt, which scan has already consumed).
//   - GEMM1: bf16 MFMA 16x16x32, C via LDS round-trip (16B stores).
// ---------------------------------------------------------------------------

typedef unsigned int uint;
typedef unsigned short u16;
typedef uint  uint4e  __attribute__((ext_vector_type(4)));
typedef float float4e __attribute__((ext_vector_type(4)));
typedef uint  uint2e  __attribute__((ext_vector_type(2)));
typedef int   int2e   __attribute__((ext_vector_type(2)));
typedef int   int4e   __attribute__((ext_vector_type(4)));
using bf16x8 = __attribute__((ext_vector_type(8))) short;
using f32x4  = __attribute__((ext_vector_type(4))) float;

__device__ __forceinline__ float bf_lo(uint v) { return __uint_as_float(v << 16); }
__device__ __forceinline__ float bf_hi(uint v) { return __uint_as_float(v & 0xffff0000u); }
__device__ __forceinline__ u16 bf16_1(float a) {
    uint ua = __float_as_uint(a);
    ua = (ua + 0x7fffu + ((ua >> 16) & 1u)) >> 16;          // RNE
    return (u16)ua;
}
__device__ __forceinline__ uint pack_bf2(float a, float b) {
    return (uint)bf16_1(a) | ((uint)bf16_1(b) << 16);
}

// Blocks [0, NCB): histogram of dst degrees. Block NCB: Wt1 transpose.
// Block NCB+1: W23 = W2@W3, b23 = b2@W3.
__global__ __launch_bounds__(256) void count_wt_kernel(const int* __restrict__ ei, int E,
        int* __restrict__ cnt, const float* __restrict__ W1, const float* __restrict__ W2,
        const float* __restrict__ W3, const float* __restrict__ b2,
        u16* __restrict__ Wt1, float* __restrict__ W23, float* __restrict__ b23, int ncb) {
    int tid = threadIdx.x;
    if ((int)blockIdx.x < ncb) {
        int i = blockIdx.x * 256 + tid;
        int stride = ncb * 256;
        int nG = E >> 2;
        for (int g = i; g < nG; g += stride) {
            int4e d = *reinterpret_cast<const int4e*>(ei + E + g * 4);
            atomicAdd(&cnt[d.x], 1);
            atomicAdd(&cnt[d.y], 1);
            atomicAdd(&cnt[d.z], 1);
            atomicAdd(&cnt[d.w], 1);
        }
        for (int e = nG * 4 + i; e < E; e += stride) atomicAdd(&cnt[ei[E + e]], 1);
    } else if ((int)blockIdx.x == ncb) {
        for (int i = 0; i < 64; ++i) {
            int idx = tid + i * 256;          // 16384 = 128*128
            int k = idx >> 7, c = idx & 127;
            Wt1[c * 128 + k] = bf16_1(W1[idx]);
        }
    } else {
        __shared__ float w3s[1280];
        for (int i = tid; i < 1280; i += 256) w3s[i] = W3[i];
        __syncthreads();
#pragma unroll
        for (int i = 0; i < 5; ++i) {
            int idx = tid * 5 + i;            // 1280 outputs
            int k = idx / 10, c = idx % 10;
            float acc = 0.f;
            for (int j = 0; j < 128; ++j) acc += W2[k * 128 + j] * w3s[j * 10 + c];
            W23[idx] = acc;
        }
        if (tid < 10) {
            float acc = 0.f;
            for (int j = 0; j < 128; ++j) acc += b2[j] * w3s[j * 10 + tid];
            b23[tid] = acc;
        }
    }
}

// Pass 1: per-block (1024 elems) totals; also computes dis = rsqrt(deg+1).
__global__ __launch_bounds__(256) void scan_partial(const int* __restrict__ cnt,
        int* __restrict__ bsum, float* __restrict__ dis, int n) {
    __shared__ int red[256];
    int b = blockIdx.x, tid = threadIdx.x;
    int base = b * 1024 + tid * 4;
    int4 v = make_int4(0, 0, 0, 0);
    if (base + 4 <= n) {
        v = *reinterpret_cast<const int4*>(cnt + base);
    } else {
        if (base + 0 < n) v.x = cnt[base + 0];
        if (base + 1 < n) v.y = cnt[base + 1];
        if (base + 2 < n) v.z = cnt[base + 2];
    }
    if (base + 0 < n) dis[base + 0] = rsqrtf((float)(v.x + 1));
    if (base + 1 < n) dis[base + 1] = rsqrtf((float)(v.y + 1));
    if (base + 2 < n) dis[base + 2] = rsqrtf((float)(v.z + 1));
    if (base + 3 < n) dis[base + 3] = rsqrtf((float)(v.w + 1));
    red[tid] = v.x + v.y + v.z + v.w;
    __syncthreads();
    for (int d = 128; d > 0; d >>= 1) {
        if (tid < d) red[tid] += red[tid + d];
        __syncthreads();
    }
    if (tid == 0) bsum[b] = red[0];
}

// Pass 2: wave 0 redundantly scans block sums for this block's offset, then
// block-local exclusive scan + offset -> row_ptr.
__global__ __launch_bounds__(256) void scan_final(const int* __restrict__ cnt,
        const int* __restrict__ bsum, int* __restrict__ row_ptr, int nb, int n) {
    __shared__ int red[256];
    __shared__ int sh_boff;
    int b = blockIdx.x, tid = threadIdx.x;
    if (tid < 64) {
        int s = (tid < nb) ? bsum[tid] : 0;
        int v = s;
        for (int d = 1; d < 64; d <<= 1) {
            int t = __shfl_up(v, d);
            if (tid >= d) v += t;
        }
        if (tid == b) sh_boff = v - s;                 // exclusive offset of this block
        if (b == 0 && tid == 63) row_ptr[n] = v;       // grand total
    }
    int base = b * 1024 + tid * 4;
    int4 v = make_int4(0, 0, 0, 0);
    if (base + 4 <= n) {
        v = *reinterpret_cast<const int4*>(cnt + base);
    } else {
        if (base + 0 < n) v.x = cnt[base + 0];
        if (base + 1 < n) v.y = cnt[base + 1];
        if (base + 2 < n) v.z = cnt[base + 2];
    }
    int s = v.x + v.y + v.z + v.w;
    red[tid] = s;
    __syncthreads();
    for (int d = 1; d < 256; d <<= 1) {
        int t = (tid >= d) ? red[tid - d] : 0;
        __syncthreads();
        red[tid] += t;
        __syncthreads();
    }
    int off = sh_boff + red[tid] - s;
    if (base + 0 < n) { row_ptr[base + 0] = off; off += v.x; }
    if (base + 1 < n) { row_ptr[base + 1] = off; off += v.y; }
    if (base + 2 < n) { row_ptr[base + 2] = off; off += v.z; }
    if (base + 3 < n) { row_ptr[base + 3] = off; }
}

// Fused: blocks [0, gemmBlocks) do the MFMA GEMM; the rest do CSR fill.
// Fill counts DOWN on cnt (deg -> 0): slot = atomicSub(cnt[d])-1.
// The two halves are independent; co-execution hides the GEMM.
__global__ __launch_bounds__(256) void fill_gemm_kernel(
        const int* __restrict__ ei, int E, const int* __restrict__ row_ptr,
        int* __restrict__ cnt, const float* __restrict__ dis, int2e* __restrict__ esort,
        const float* __restrict__ A, const u16* __restrict__ Wt, u16* __restrict__ out,
        int n, int gemmBlocks) {
    int tid = threadIdx.x;
    if ((int)blockIdx.x >= gemmBlocks) {
        // ---------------- fill half ----------------
        int fb = blockIdx.x - gemmBlocks;
        int nfb = gridDim.x - gemmBlocks;
        int i = fb * 256 + tid;
        int stride = nfb * 256;
        int nG = E >> 2;
        for (int g = i; g < nG; g += stride) {
            int4e s4 = *reinterpret_cast<const int4e*>(ei + g * 4);
            int4e d4 = *reinterpret_cast<const int4e*>(ei + E + g * 4);
#pragma unroll
            for (int k = 0; k < 4; ++k) {
                int s = k == 0 ? s4.x : k == 1 ? s4.y : k == 2 ? s4.z : s4.w;
                int d = k == 0 ? d4.x : k == 1 ? d4.y : k == 2 ? d4.z : d4.w;
                int pos = row_ptr[d] + atomicSub(&cnt[d], 1) - 1;
                int2e pkt;
                pkt.x = s;
                pkt.y = __float_as_int(dis[s] * dis[d]);
                esort[pos] = pkt;
            }
        }
        for (int e = nG * 4 + i; e < E; e += stride) {
            int s = ei[e];
            int d = ei[E + e];
            int pos = row_ptr[d] + atomicSub(&cnt[d], 1) - 1;
            int2e pkt;
            pkt.x = s;
            pkt.y = __float_as_int(dis[s] * dis[d]);
            esort[pos] = pkt;
        }
        return;
    }
    // ---------------- GEMM half: out = bf16(A @ W), Wt bf16 [col][k] ----------------
    constexpr int LDA = 136;                 // 128 + 8 pad (bf16) -> 2-way LDS only
    __shared__ u16 as[64 * LDA];
    int wave = tid >> 6, lane = tid & 63;
    int row0 = blockIdx.x * 64;
    int l16 = lane & 15;
    int krow = (lane >> 4) * 8;              // k-octet within 32-wide K block

#pragma unroll
    for (int i = 0; i < 8; ++i) {
        int idx = tid + i * 256;             // 2048 quads of 4 f32
        int r = idx >> 5;
        int q = (idx & 31) * 4;
        float4e v = {0.f, 0.f, 0.f, 0.f};
        if (row0 + r < n)
            v = *reinterpret_cast<const float4e*>(A + (size_t)(row0 + r) * 128 + q);
        uint2e p;
        p.x = pack_bf2(v.x, v.y);
        p.y = pack_bf2(v.z, v.w);
        *reinterpret_cast<uint2e*>(&as[r * LDA + q]) = p;
    }

    bf16x8 b[2][4];
#pragma unroll
    for (int n2 = 0; n2 < 2; ++n2)
#pragma unroll
        for (int kb = 0; kb < 4; ++kb)
            b[n2][kb] = *reinterpret_cast<const bf16x8*>(
                Wt + (size_t)(wave * 32 + n2 * 16 + l16) * 128 + kb * 32 + krow);

    __syncthreads();

    f32x4 acc[4][2] = {};
#pragma unroll
    for (int m = 0; m < 4; ++m) {
#pragma unroll
        for (int kb = 0; kb < 4; ++kb) {
            bf16x8 a = *reinterpret_cast<const bf16x8*>(
                &as[(m * 16 + l16) * LDA + kb * 32 + krow]);
#pragma unroll
            for (int n2 = 0; n2 < 2; ++n2)
                acc[m][n2] = __builtin_amdgcn_mfma_f32_16x16x32_bf16(a, b[n2][kb], acc[m][n2], 0, 0, 0);
        }
    }

    __syncthreads();                         // as[] reuse as C-staging
    u16* cs = as;
#pragma unroll
    for (int m = 0; m < 4; ++m) {
        int rb = m * 16 + (lane >> 4) * 4;
#pragma unroll
        for (int n2 = 0; n2 < 2; ++n2) {
            int col = wave * 32 + n2 * 16 + l16;
#pragma unroll
            for (int r = 0; r < 4; ++r)
                cs[(rb + r) * 128 + col] = bf16_1(acc[m][n2][r]);
        }
    }
    __syncthreads();
#pragma unroll
    for (int i = 0; i < 4; ++i) {
        int idx = tid + i * 256;             // 1024 octs: row=idx>>4, oct=(idx&15)
        int r = idx >> 4;
        int q = (idx & 15) * 8;
        if (row0 + r < n)
            *reinterpret_cast<uint4e*>(out + (size_t)(row0 + r) * 128 + q) =
                *reinterpret_cast<const uint4e*>(&cs[r * 128 + q]);
    }
}

// Full-wave gather: lane owns dims 2*lane..2*lane+1, 8 edges in flight.
__device__ __forceinline__ void gather_accum(const uint* __restrict__ xw,
        const int2e* __restrict__ esort, const float* __restrict__ dis,
        int v, int lane, int beg, int end, float& ax, float& ay) {
    int e = beg;
    for (; e + 7 < end; e += 8) {
        int2e ed[8];
        uint vv[8];
#pragma unroll
        for (int j = 0; j < 8; ++j) ed[j] = esort[e + j];
#pragma unroll
        for (int j = 0; j < 8; ++j) vv[j] = xw[(size_t)ed[j].x * 64 + lane];
#pragma unroll
        for (int j = 0; j < 8; ++j) {
            float w = __int_as_float(ed[j].y);
            ax += w * bf_lo(vv[j]);
            ay += w * bf_hi(vv[j]);
        }
    }
    for (; e + 1 < end; e += 2) {
        int2e e0 = esort[e];
        int2e e1 = esort[e + 1];
        uint v0 = xw[(size_t)e0.x * 64 + lane];
        uint v1 = xw[(size_t)e1.x * 64 + lane];
        float w0 = __int_as_float(e0.y), w1 = __int_as_float(e1.y);
        ax += w0 * bf_lo(v0); ay += w0 * bf_hi(v0);
        ax += w1 * bf_lo(v1); ay += w1 * bf_hi(v1);
    }
    if (e < end) {
        int2e e0 = esort[e];
        uint v0 = xw[(size_t)e0.x * 64 + lane];
        float w0 = __int_as_float(e0.y);
        ax += w0 * bf_lo(v0); ay += w0 * bf_hi(v0);
    }
    float dv = dis[v];
    float wv = dv * dv;                            // self-loop norm
    uint vs = xw[(size_t)v * 64 + lane];
    ax += wv * bf_lo(vs); ay += wv * bf_hi(vs);
}

// Pass A: z[v][0..9] = relu(Agg(x@W1)[v] + b1) @ W23   (the one big gather).
__global__ __launch_bounds__(256) void agg_proj_kernel(const uint* __restrict__ xw,
        const int* __restrict__ row_ptr, const int2e* __restrict__ esort,
        const float* __restrict__ dis, const float* __restrict__ b1,
        const float* __restrict__ W23, float* __restrict__ z, int n) {
    int v = (int)((blockIdx.x * blockDim.x + threadIdx.x) >> 6);
    int lane = threadIdx.x & 63;
    if (v >= n) return;
    float ax = 0.f, ay = 0.f;
    gather_accum(xw, esort, dis, v, lane, row_ptr[v], row_ptr[v + 1], ax, ay);
    ax = fmaxf(ax + b1[lane * 2], 0.f);
    ay = fmaxf(ay + b1[lane * 2 + 1], 0.f);
    const float* w0 = W23 + (size_t)lane * 20;     // this lane's 2 rows of W23
    float p[10];
#pragma unroll
    for (int c = 0; c < 10; ++c) p[c] = ax * w0[c] + ay * w0[10 + c];
#pragma unroll
    for (int c = 0; c < 10; ++c) {
#pragma unroll
        for (int d = 1; d < 64; d <<= 1) p[c] += __shfl_xor(p[c], d);
    }
    if (lane < 10) z[(size_t)v * 10 + lane] = p[lane];
}

// Pass B/C: 10-dim aggregation, 4 nodes per wave (16-lane groups, lanes 0-9
// of each group carry dims). FINAL=0: zout = Agg(zin).
// FINAL=1: out = log_softmax(Agg(zin) + s*b23 + b3).
template <int FINAL>
__global__ __launch_bounds__(256) void agg10_kernel(const float* __restrict__ zin,
        const int* __restrict__ row_ptr, const int2e* __restrict__ esort,
        const float* __restrict__ dis, const float* __restrict__ b23,
        const float* __restrict__ b3, float* __restrict__ zout, int n) {
    int wid = (int)((blockIdx.x * blockDim.x + threadIdx.x) >> 6);
    int lane = threadIdx.x & 63;
    int grp = lane >> 4, gl = lane & 15;
    int v = wid * 4 + grp;
    bool act = (v < n);
    bool dl = (gl < 10);
    int beg = act ? row_ptr[v] : 0;
    int end = act ? row_ptr[v + 1] : 0;
    float acc = 0.f, sw = 0.f;
    int e = beg;
    for (; e + 3 < end; e += 4) {
        int2e e0 = esort[e], e1 = esort[e + 1], e2 = esort[e + 2], e3 = esort[e + 3];
        float z0 = dl ? zin[(size_t)e0.x * 10 + gl] : 0.f;
        float z1 = dl ? zin[(size_t)e1.x * 10 + gl] : 0.f;
        float z2 = dl ? zin[(size_t)e2.x * 10 + gl] : 0.f;
        float z3 = dl ? zin[(size_t)e3.x * 10 + gl] : 0.f;
        float w0 = __int_as_float(e0.y), w1 = __int_as_float(e1.y);
        float w2 = __int_as_float(e2.y), w3 = __int_as_float(e3.y);
        acc += w0 * z0 + w1 * z1 + w2 * z2 + w3 * z3;
        sw += (w0 + w1) + (w2 + w3);
    }
    for (; e < end; ++e) {
        int2e e0 = esort[e];
        float z0 = dl ? zin[(size_t)e0.x * 10 + gl] : 0.f;
        float w0 = __int_as_float(e0.y);
        acc += w0 * z0;
        sw += w0;
    }
    if (act) {
        float dv = dis[v];
        float wv = dv * dv;                        // self-loop
        float zs = dl ? zin[(size_t)v * 10 + gl] : 0.f;
        acc += wv * zs;
        sw += wv;
    }
    if (FINAL == 0) {
        if (act && dl) zout[(size_t)v * 10 + gl] = acc;
    } else {
        float p = acc + (dl ? sw * b23[gl] + b3[gl] : 0.f);
        float m = dl ? p : -3.4e38f;
#pragma unroll
        for (int mask = 1; mask < 16; mask <<= 1) m = fmaxf(m, __shfl_xor(m, mask));
        float s = dl ? __expf(p - m) : 0.f;
#pragma unroll
        for (int mask = 1; mask < 16; mask <<= 1) s += __shfl_xor(s, mask);
        float ls = __logf(s);
        if (act && dl) zout[(size_t)v * 10 + gl] = p - m - ls;
    }
}

extern "C" void kernel_launch(void* const* d_in, const int* in_sizes, int n_in,
                              void* d_out, int out_size, void* d_ws, size_t ws_size,
                              hipStream_t stream) {
    const float* x  = (const float*)d_in[0];
    const int*   ei = (const int*)d_in[1];   // [2][E] int32
    const float* W1 = (const float*)d_in[2];
    const float* b1 = (const float*)d_in[3];
    const float* W2 = (const float*)d_in[4];
    const float* b2 = (const float*)d_in[5];
    const float* W3 = (const float*)d_in[6];
    const float* b3 = (const float*)d_in[7];
    int N = in_sizes[0] / 128;
    int E = in_sizes[1] / 2;
    int NB = (N + 1023) / 1024;   // 49 for N=50000 (must be <= 64)

    char* ws = (char*)d_ws;
    size_t off = 0;
    auto alloc = [&](size_t bytes) -> char* {
        char* p = ws + off;
        off = (off + bytes + 255) & ~(size_t)255;
        return p;
    };
    int*   cnt     = (int*)alloc((size_t)N * 4);
    int*   row_ptr = (int*)alloc(((size_t)N + 1) * 4);
    float* dis     = (float*)alloc((size_t)N * 4);
    int*   bsum    = (int*)alloc(64 * 4);
    u16*   Wt1     = (u16*)alloc(128 * 128 * 2);
    float* W23     = (float*)alloc(128 * 10 * 4);
    float* b23     = (float*)alloc(10 * 4);
    int2e* esort   = (int2e*)alloc((size_t)E * 8);
    uint*  bufA    = (uint*)alloc((size_t)N * 64 * 4);   // bf16x2 packed x@W1
    float* z       = (float*)alloc((size_t)N * 10 * 4);  // h1@W23  (2MB, L2-fits)
    float* z2      = (float*)alloc((size_t)N * 10 * 4);  // Agg(z)

    (void)hipMemsetAsync(cnt, 0, (size_t)N * 4, stream);

    const int NCB = 1024;          // counting blocks
    const int GEMMB = (N + 63) / 64;
    const int FILLB = 1024;

    // --- preprocessing: degree histogram + weight prep (fused) ---
    count_wt_kernel<<<NCB + 2, 256, 0, stream>>>(ei, E, cnt, W1, W2, W3, b2,
                                                 Wt1, W23, b23, NCB);
    scan_partial<<<NB, 256, 0, stream>>>(cnt, bsum, dis, N);
    scan_final<<<NB, 256, 0, stream>>>(cnt, bsum, row_ptr, NB, N);
    // --- CSR fill + layer-1 GEMM co-executing (independent halves) ---
    fill_gemm_kernel<<<GEMMB + FILLB, 256, 0, stream>>>(ei, E, row_ptr, cnt, dis, esort,
                                                        x, Wt1, (u16*)bufA, N, GEMMB);
    // --- the single 128-dim gather, fused with ReLU+projection ---
    agg_proj_kernel<<<(N + 3) / 4, 256, 0, stream>>>(bufA, row_ptr, esort, dis, b1, W23, z, N);
    // --- layers 2+3: two 10-dim aggregations (L2-resident table) ---
    agg10_kernel<0><<<(N + 15) / 16, 256, 0, stream>>>(z, row_ptr, esort, dis, nullptr, nullptr, z2, N);
    agg10_kernel<1><<<(N + 15) / 16, 256, 0, stream>>>(z2, row_ptr, esort, dis, b23, b3, (float*)d_out, N);
}